// Round 7
// baseline (637.013 us; speedup 1.0000x reference)
//
#include <hip/hip_runtime.h>

// MoE-INR fused megakernel, bf16 MFMA (gfx950). Round 7:
// - 32-row tiles (35.5KB LDS -> 4 blocks/CU) with launch_bounds(256,2):
//   r6's (256,4) made the compiler pick VGPR=64 + spill 67MB of scratch;
//   (256,2) gave spill-free VGPR=120 in r3/r5. 120<=128 still allows
//   4 waves/SIMD, so 16 waves/CU of independent barrier domains.
// - Swapped-operand wgemm: A=W(global), B=activation(LDS) => D[feat][batch];
//   each lane holds 4 consecutive features -> packed ds_write_b64 epilogue
//   (16/wave vs 64 scalar b16), float4 bias loads, b64 skip reads.

typedef short v8s __attribute__((ext_vector_type(8)));
typedef float v4f __attribute__((ext_vector_type(4)));

#define OMEGA_F 30.0f
#define AST 264   // LDS row stride in bf16 elements (528B: %16B=0, banks +4/row)
#define N_CVT 8

__device__ __forceinline__ float bf2f(unsigned short h) {
  union { unsigned u; float f; } v; v.u = ((unsigned)h) << 16; return v.f;
}
__device__ __forceinline__ unsigned short f2bf(float f) {
  union { float f; unsigned u; } v; v.f = f;
  unsigned r = v.u + 0x7fffu + ((v.u >> 16) & 1u);  // RNE
  return (unsigned short)(r >> 16);
}
__device__ __forceinline__ unsigned pack2(float lo, float hi) {
  return (unsigned)f2bf(lo) | ((unsigned)f2bf(hi) << 16);
}

struct CvtArgs {
  const float* src[N_CVT];
  unsigned     off[N_CVT];
  unsigned     n[N_CVT];   // all divisible by 4
};

typedef float v4fv __attribute__((ext_vector_type(4)));
typedef unsigned short v4u16 __attribute__((ext_vector_type(4)));

__global__ void convert_kernel(CvtArgs a, unsigned short* __restrict__ dst) {
  const int tid = blockIdx.x * blockDim.x + threadIdx.x;
  const int stride = gridDim.x * blockDim.x;
  for (int k = 0; k < N_CVT; k++) {
    const unsigned n4 = a.n[k] >> 2;
    const v4fv* s = (const v4fv*)a.src[k];
    v4u16* d = (v4u16*)(dst + a.off[k]);
    for (unsigned i = tid; i < n4; i += stride) {
      v4fv v = s[i];
      v4u16 o;
      o.x = f2bf(v.x); o.y = f2bf(v.y); o.z = f2bf(v.z); o.w = f2bf(v.w);
      d[i] = o;
    }
  }
}

// ------------- swapped-operand wave GEMM (4 waves, 32 batch rows) ----------
// OUT[b][oc+o] = act( sum_k A[b][k] * W[o][k] + bias[o] ), o in [0,OUT)
// MFMA: Amat = W rows (global), Bmat = activations (LDS [b][k], stride AST).
// D[m=o][n=b]. Wave w covers o in [w*OUT/4,(w+1)*OUT/4); all 32 b.
// ACT: 0=sin(30z), 1=relu, 2=relu(z+skip)
template<int K, int OUT, int ACT>
__device__ __forceinline__ void wgemm_s(const unsigned short* A,
                                        unsigned short* OUTP, int oc,
                                        const unsigned short* __restrict__ W,
                                        const float* __restrict__ bias,
                                        const unsigned short* skip) {
  constexpr int RT = OUT / 64;
  constexpr int KI = K / 32;
  const int lane = threadIdx.x & 63;
  const int wave = threadIdx.x >> 6;
  const int m15  = lane & 15;
  const int q    = lane >> 4;
  const int n0w  = wave * (OUT / 4);
  v4f acc[RT][2];
#pragma unroll
  for (int i = 0; i < RT; i++)
#pragma unroll
    for (int j = 0; j < 2; j++) acc[i][j] = (v4f){0.f, 0.f, 0.f, 0.f};

#pragma unroll
  for (int k0 = 0; k0 < KI; ++k0) {
    v8s af[RT], bf[2];
#pragma unroll
    for (int rt = 0; rt < RT; rt++)
      af[rt] = *(const v8s*)(W + (size_t)(n0w + rt * 16 + m15) * K + k0 * 32 + q * 8);
#pragma unroll
    for (int ct = 0; ct < 2; ct++)
      bf[ct] = *(const v8s*)(A + (ct * 16 + m15) * AST + k0 * 32 + q * 8);
#pragma unroll
    for (int rt = 0; rt < RT; rt++)
#pragma unroll
      for (int ct = 0; ct < 2; ct++)
        acc[rt][ct] = __builtin_amdgcn_mfma_f32_16x16x32_bf16(af[rt], bf[ct], acc[rt][ct], 0, 0, 0);
  }

#pragma unroll
  for (int ct = 0; ct < 2; ct++) {
    const int b = ct * 16 + m15;
#pragma unroll
    for (int rt = 0; rt < RT; rt++) {
      const int o0 = n0w + rt * 16 + q * 4;
      const v4f bv = *(const v4f*)(bias + o0);
      float z[4];
#pragma unroll
      for (int r = 0; r < 4; r++) z[r] = acc[rt][ct][r] + bv[r];
      if (ACT == 2) {
        uint2 sv = *(const uint2*)(skip + b * AST + oc + o0);
        z[0] += bf2f((unsigned short)(sv.x & 0xffffu));
        z[1] += bf2f((unsigned short)(sv.x >> 16));
        z[2] += bf2f((unsigned short)(sv.y & 0xffffu));
        z[3] += bf2f((unsigned short)(sv.y >> 16));
      }
      float o[4];
#pragma unroll
      for (int r = 0; r < 4; r++) {
        if (ACT == 0) o[r] = __sinf(OMEGA_F * z[r]);
        else          o[r] = fmaxf(z[r], 0.f);
      }
      uint2 pk;
      pk.x = pack2(o[0], o[1]);
      pk.y = pack2(o[2], o[3]);
      *(uint2*)(OUTP + b * AST + oc + o0) = pk;
    }
  }
}

// Expert layer 2 fused with final 256->1 dot (swapped operands).
// D[m=o2][n=b]; per-lane partial dot over its o2, reduce across q via shfl.
__device__ __forceinline__ void wexpert2_s(const unsigned short* A,
                                           const unsigned short* __restrict__ W,
                                           const float* __restrict__ bias,
                                           const float* __restrict__ wfin,
                                           float* predw /* [4][32] */) {
  const int lane = threadIdx.x & 63;
  const int wave = threadIdx.x >> 6;
  const int m15  = lane & 15;
  const int q    = lane >> 4;
  const int n0w  = wave * 64;
  v4f acc[4][2];
#pragma unroll
  for (int i = 0; i < 4; i++)
#pragma unroll
    for (int j = 0; j < 2; j++) acc[i][j] = (v4f){0.f, 0.f, 0.f, 0.f};

#pragma unroll
  for (int k0 = 0; k0 < 8; ++k0) {
    v8s af[4], bf[2];
#pragma unroll
    for (int rt = 0; rt < 4; rt++)
      af[rt] = *(const v8s*)(W + (size_t)(n0w + rt * 16 + m15) * 256 + k0 * 32 + q * 8);
#pragma unroll
    for (int ct = 0; ct < 2; ct++)
      bf[ct] = *(const v8s*)(A + (ct * 16 + m15) * AST + k0 * 32 + q * 8);
#pragma unroll
    for (int rt = 0; rt < 4; rt++)
#pragma unroll
      for (int ct = 0; ct < 2; ct++)
        acc[rt][ct] = __builtin_amdgcn_mfma_f32_16x16x32_bf16(af[rt], bf[ct], acc[rt][ct], 0, 0, 0);
  }

  float p[2] = {0.f, 0.f};
#pragma unroll
  for (int rt = 0; rt < 4; rt++) {
    const int o0 = n0w + rt * 16 + q * 4;
    const v4f bv = *(const v4f*)(bias + o0);
    const v4f wv = *(const v4f*)(wfin + o0);
#pragma unroll
    for (int ct = 0; ct < 2; ct++)
#pragma unroll
      for (int r = 0; r < 4; r++)
        p[ct] += __sinf(OMEGA_F * (acc[rt][ct][r] + bv[r])) * wv[r];
  }
#pragma unroll
  for (int ct = 0; ct < 2; ct++) {
    float v = p[ct];
    v += __shfl_xor(v, 16);
    v += __shfl_xor(v, 32);
    if (q == 0) predw[wave * 32 + ct * 16 + m15] = v;
  }
}

__global__ __launch_bounds__(256, 2) void moe_inr_kernel(
    const float* __restrict__ x,
    const unsigned short* __restrict__ es1w, const float* __restrict__ es1b,
    const unsigned short* __restrict__ es2w, const float* __restrict__ es2b,
    const unsigned short* __restrict__ rf1w, const float* __restrict__ rf1b,
    const unsigned short* __restrict__ rf2w, const float* __restrict__ rf2b,
    const unsigned short* __restrict__ rf3w, const float* __restrict__ rf3b,
    const float* __restrict__ ps1w,          const float* __restrict__ ps1b,
    const unsigned short* __restrict__ ps2w, const float* __restrict__ ps2b,
    const float* __restrict__ gw,            const float* __restrict__ gb,
    const unsigned short* __restrict__ xs1w, const float* __restrict__ xs1b,
    const unsigned short* __restrict__ xs2w, const float* __restrict__ xs2b,
    const float* __restrict__ xfw,           const float* __restrict__ xfb,
    float* __restrict__ out) {
  __shared__ __align__(16) unsigned short P[32 * AST];
  __shared__ __align__(16) unsigned short Q[32 * AST];
  __shared__ float probs[32 * 8];
  __shared__ float yacc[32];
  __shared__ float predw[4 * 32];

  const int t  = threadIdx.x;
  const int r0 = blockIdx.x * 32;

  // Stage 0: positional encoding in f32 -> P[b][0..64)
  {
    const int row = t & 31, g = t >> 5, c = g & 3, jh = g >> 2;
    const float xv = x[(r0 + row) * 4 + c];
    const float PIf = 3.14159265358979f;
#pragma unroll
    for (int jj = 0; jj < 4; jj++) {
      const int j = jh * 4 + jj;
      float ang = xv * (PIf * (float)(1 << j));
      P[row * AST + c * 16 + j]     = f2bf(__sinf(ang));
      P[row * AST + c * 16 + 8 + j] = f2bf(__cosf(ang));
    }
    if (t < 32) yacc[t] = 0.f;
  }
  __syncthreads();
  wgemm_s<64, 128, 0>(P, P, 64, es1w, es1b, nullptr);       // h1 -> P[64,192)
  __syncthreads();
  wgemm_s<128, 256, 0>(P + 64, Q, 0, es2w, es2b, nullptr);  // h  -> Q[0,256)
  __syncthreads();
  wgemm_s<256, 128, 1>(Q, P, 0, rf1w, rf1b, nullptr);       // r1 -> P[0,128)
  __syncthreads();
  wgemm_s<128, 128, 1>(P, P, 128, rf2w, rf2b, nullptr);     // r2 -> P[128,256)
  __syncthreads();
  wgemm_s<128, 256, 2>(P + 128, Q, 0, rf3w, rf3b, Q);       // enc_feat -> Q
  __syncthreads();
  // pol_s1 (K=4) in f32: pf1 -> P[0,128)
  {
    const int row = t & 31, g = t >> 5;
    const float xv0 = x[(r0 + row) * 4 + 0];
    const float xv1 = x[(r0 + row) * 4 + 1];
    const float xv2 = x[(r0 + row) * 4 + 2];
    const float xv3 = x[(r0 + row) * 4 + 3];
    for (int i = 0; i < 16; i++) {
      int o = g * 16 + i;
      float z = xv0 * ps1w[o * 4 + 0] + xv1 * ps1w[o * 4 + 1] +
                xv2 * ps1w[o * 4 + 2] + xv3 * ps1w[o * 4 + 3] + ps1b[o];
      P[row * AST + o] = f2bf(__sinf(OMEGA_F * z));
    }
  }
  __syncthreads();
  wgemm_s<128, 128, 0>(P, P, 128, ps2w, ps2b, nullptr);     // pf -> P[128,256)
  __syncthreads();
  // gate (f32 weights): 8 partial-threads per row (48 k each)
  {
    const int row = t >> 3, pp = t & 7;
    float lg[7];
#pragma unroll
    for (int j = 0; j < 7; j++) {
      float s = 0.f;
      for (int kk = pp * 48; kk < pp * 48 + 48; ++kk) {
        float v = (kk < 256) ? bf2f(Q[row * AST + kk])
                             : bf2f(P[row * AST + 128 + (kk - 256)]);
        s += v * gw[j * 384 + kk];
      }
      s += __shfl_xor(s, 1);
      s += __shfl_xor(s, 2);
      s += __shfl_xor(s, 4);
      lg[j] = s;
    }
    if (pp == 0) {
#pragma unroll
      for (int j = 0; j < 7; j++) probs[row * 8 + j] = lg[j] + gb[j];
    }
  }
  __syncthreads();
  if (t < 32) {  // softmax over 7
    float m = probs[t * 8];
#pragma unroll
    for (int j = 1; j < 7; j++) m = fmaxf(m, probs[t * 8 + j]);
    float s = 0.f, e[7];
#pragma unroll
    for (int j = 0; j < 7; j++) { e[j] = __expf(probs[t * 8 + j] - m); s += e[j]; }
    float inv = 1.f / s;
#pragma unroll
    for (int j = 0; j < 7; j++) probs[t * 8 + j] = e[j] * inv;
  }
  // experts: enc_feat stays in Q; e1 -> P[0,256); e2+final fused in registers
  for (int ex = 0; ex < 7; ++ex) {
    __syncthreads();
    wgemm_s<256, 256, 0>(Q, P, 0, xs1w + ex * 65536, xs1b + ex * 256, nullptr);
    __syncthreads();
    wexpert2_s(P, xs2w + ex * 65536, xs2b + ex * 256, xfw + ex * 256, predw);
    __syncthreads();
    if (t < 32)
      yacc[t] += (predw[t] + predw[32 + t] + predw[64 + t] + predw[96 + t] +
                  xfb[ex]) * probs[t * 8 + ex];
  }
  __syncthreads();
  if (t < 32) out[r0 + t] = yacc[t];
}

extern "C" void kernel_launch(void* const* d_in, const int* in_sizes, int n_in,
                              void* d_out, int out_size, void* d_ws, size_t ws_size,
                              hipStream_t stream) {
  (void)out_size; (void)n_in; (void)ws_size;
  const int idx[N_CVT] = {1, 3, 5, 7, 9, 13, 17, 19};
  unsigned off[N_CVT], cur = 0;
  CvtArgs a;
  for (int i = 0; i < N_CVT; i++) {
    off[i] = cur;
    a.src[i] = (const float*)d_in[idx[i]];
    a.off[i] = cur;
    a.n[i]   = (unsigned)in_sizes[idx[i]];
    cur += ((unsigned)in_sizes[idx[i]] + 7u) & ~7u;  // 16B-align each array
  }
  unsigned short* dst = (unsigned short*)d_ws;
  hipLaunchKernelGGL(convert_kernel, dim3(512), dim3(256), 0, stream, a, dst);
  hipLaunchKernelGGL(moe_inr_kernel, dim3(65536 / 32), dim3(256), 0, stream,
      (const float*)d_in[0],
      dst + off[0], (const float*)d_in[2],
      dst + off[1], (const float*)d_in[4],
      dst + off[2], (const float*)d_in[6],
      dst + off[3], (const float*)d_in[8],
      dst + off[4], (const float*)d_in[10],
      (const float*)d_in[11], (const float*)d_in[12],
      dst + off[5], (const float*)d_in[14],
      (const float*)d_in[15], (const float*)d_in[16],
      dst + off[6], (const float*)d_in[18],
      dst + off[7], (const float*)d_in[20],
      (const float*)d_in[21], (const float*)d_in[22],
      (float*)d_out);
}

// Round 8
// 461.645 us; speedup vs baseline: 1.3799x; 1.3799x over previous
//
#include <hip/hip_runtime.h>

// MoE-INR fused megakernel, bf16 MFMA (gfx950). Round 8:
// 64-row tiles (r3's best block shape: block-count model says fat blocks win)
// x 512 threads (8 waves) with launch_bounds(512,2) -> spill-free codegen
// (arg=2 gave no spills in r3/r5/r7; r4/r6's arg=4 caused VGPR=64 + 67-156MB
// scratch). Target: 16 spill-free waves/CU, the one unexplored occupancy
// point. Swapped-operand wgemm (r7): A=W(global), B=act(LDS), D[feat][batch]
// -> packed b64 epilogue writes, float4 bias loads.

typedef short v8s __attribute__((ext_vector_type(8)));
typedef float v4f __attribute__((ext_vector_type(4)));

#define OMEGA_F 30.0f
#define AST 264   // LDS row stride in bf16 elements
#define N_CVT 8

__device__ __forceinline__ float bf2f(unsigned short h) {
  union { unsigned u; float f; } v; v.u = ((unsigned)h) << 16; return v.f;
}
__device__ __forceinline__ unsigned short f2bf(float f) {
  union { float f; unsigned u; } v; v.f = f;
  unsigned r = v.u + 0x7fffu + ((v.u >> 16) & 1u);  // RNE
  return (unsigned short)(r >> 16);
}
__device__ __forceinline__ unsigned pack2(float lo, float hi) {
  return (unsigned)f2bf(lo) | ((unsigned)f2bf(hi) << 16);
}

struct CvtArgs {
  const float* src[N_CVT];
  unsigned     off[N_CVT];
  unsigned     n[N_CVT];   // all divisible by 4
};

typedef float v4fv __attribute__((ext_vector_type(4)));
typedef unsigned short v4u16 __attribute__((ext_vector_type(4)));

__global__ void convert_kernel(CvtArgs a, unsigned short* __restrict__ dst) {
  const int tid = blockIdx.x * blockDim.x + threadIdx.x;
  const int stride = gridDim.x * blockDim.x;
  for (int k = 0; k < N_CVT; k++) {
    const unsigned n4 = a.n[k] >> 2;
    const v4fv* s = (const v4fv*)a.src[k];
    v4u16* d = (v4u16*)(dst + a.off[k]);
    for (unsigned i = tid; i < n4; i += stride) {
      v4fv v = s[i];
      v4u16 o;
      o.x = f2bf(v.x); o.y = f2bf(v.y); o.z = f2bf(v.z); o.w = f2bf(v.w);
      d[i] = o;
    }
  }
}

// ------- swapped-operand wave GEMM (8 waves, 64 batch rows) -------
// OUT[b][oc+o] = act( sum_k A[b][k] * W[o][k] + bias[o] )
// Amat = W rows (global), Bmat = activations (LDS, stride AST).
// D[m=o][n=b]. Wave w covers o in [w*OUT/8, (w+1)*OUT/8), all 64 b.
// ACT: 0=sin(30z), 1=relu, 2=relu(z+skip)
template<int K, int OUT, int ACT>
__device__ __forceinline__ void wgemm_s(const unsigned short* A,
                                        unsigned short* OUTP, int oc,
                                        const unsigned short* __restrict__ W,
                                        const float* __restrict__ bias,
                                        const unsigned short* skip) {
  constexpr int RT = OUT / 128;   // 16-feature tiles per wave
  constexpr int KI = K / 32;
  const int lane = threadIdx.x & 63;
  const int wave = threadIdx.x >> 6;
  const int m15  = lane & 15;
  const int q    = lane >> 4;
  const int n0w  = wave * (OUT / 8);
  v4f acc[RT][4];
#pragma unroll
  for (int i = 0; i < RT; i++)
#pragma unroll
    for (int j = 0; j < 4; j++) acc[i][j] = (v4f){0.f, 0.f, 0.f, 0.f};

#pragma unroll
  for (int k0 = 0; k0 < KI; ++k0) {
    v8s af[RT], bf[4];
#pragma unroll
    for (int rt = 0; rt < RT; rt++)
      af[rt] = *(const v8s*)(W + (size_t)(n0w + rt * 16 + m15) * K + k0 * 32 + q * 8);
#pragma unroll
    for (int ct = 0; ct < 4; ct++)
      bf[ct] = *(const v8s*)(A + (ct * 16 + m15) * AST + k0 * 32 + q * 8);
#pragma unroll
    for (int rt = 0; rt < RT; rt++)
#pragma unroll
      for (int ct = 0; ct < 4; ct++)
        acc[rt][ct] = __builtin_amdgcn_mfma_f32_16x16x32_bf16(af[rt], bf[ct], acc[rt][ct], 0, 0, 0);
  }

#pragma unroll
  for (int ct = 0; ct < 4; ct++) {
    const int b = ct * 16 + m15;
#pragma unroll
    for (int rt = 0; rt < RT; rt++) {
      const int o0 = n0w + rt * 16 + q * 4;
      const v4f bv = *(const v4f*)(bias + o0);
      float z[4];
#pragma unroll
      for (int r = 0; r < 4; r++) z[r] = acc[rt][ct][r] + bv[r];
      if (ACT == 2) {
        uint2 sv = *(const uint2*)(skip + b * AST + oc + o0);
        z[0] += bf2f((unsigned short)(sv.x & 0xffffu));
        z[1] += bf2f((unsigned short)(sv.x >> 16));
        z[2] += bf2f((unsigned short)(sv.y & 0xffffu));
        z[3] += bf2f((unsigned short)(sv.y >> 16));
      }
      float o[4];
#pragma unroll
      for (int r = 0; r < 4; r++) {
        if (ACT == 0) o[r] = __sinf(OMEGA_F * z[r]);
        else          o[r] = fmaxf(z[r], 0.f);
      }
      uint2 pk;
      pk.x = pack2(o[0], o[1]);
      pk.y = pack2(o[2], o[3]);
      *(uint2*)(OUTP + b * AST + oc + o0) = pk;
    }
  }
}

// Expert layer 2 fused with final 256->1 dot (swapped operands, 8 waves).
// Wave w covers o2 in [w*32,(w+1)*32), all 64 b; partial dot per lane,
// reduce over q via shfl; predw[wave][b].
__device__ __forceinline__ void wexpert2_s(const unsigned short* A,
                                           const unsigned short* __restrict__ W,
                                           const float* __restrict__ bias,
                                           const float* __restrict__ wfin,
                                           float* predw /* [8][64] */) {
  const int lane = threadIdx.x & 63;
  const int wave = threadIdx.x >> 6;
  const int m15  = lane & 15;
  const int q    = lane >> 4;
  const int n0w  = wave * 32;
  v4f acc[2][4];
#pragma unroll
  for (int i = 0; i < 2; i++)
#pragma unroll
    for (int j = 0; j < 4; j++) acc[i][j] = (v4f){0.f, 0.f, 0.f, 0.f};

#pragma unroll
  for (int k0 = 0; k0 < 8; ++k0) {
    v8s af[2], bf[4];
#pragma unroll
    for (int rt = 0; rt < 2; rt++)
      af[rt] = *(const v8s*)(W + (size_t)(n0w + rt * 16 + m15) * 256 + k0 * 32 + q * 8);
#pragma unroll
    for (int ct = 0; ct < 4; ct++)
      bf[ct] = *(const v8s*)(A + (ct * 16 + m15) * AST + k0 * 32 + q * 8);
#pragma unroll
    for (int rt = 0; rt < 2; rt++)
#pragma unroll
      for (int ct = 0; ct < 4; ct++)
        acc[rt][ct] = __builtin_amdgcn_mfma_f32_16x16x32_bf16(af[rt], bf[ct], acc[rt][ct], 0, 0, 0);
  }

  float p[4] = {0.f, 0.f, 0.f, 0.f};
#pragma unroll
  for (int rt = 0; rt < 2; rt++) {
    const int o0 = n0w + rt * 16 + q * 4;
    const v4f bv = *(const v4f*)(bias + o0);
    const v4f wv = *(const v4f*)(wfin + o0);
#pragma unroll
    for (int ct = 0; ct < 4; ct++)
#pragma unroll
      for (int r = 0; r < 4; r++)
        p[ct] += __sinf(OMEGA_F * (acc[rt][ct][r] + bv[r])) * wv[r];
  }
#pragma unroll
  for (int ct = 0; ct < 4; ct++) {
    float v = p[ct];
    v += __shfl_xor(v, 16);
    v += __shfl_xor(v, 32);
    if (q == 0) predw[wave * 64 + ct * 16 + m15] = v;
  }
}

__global__ __launch_bounds__(512, 2) void moe_inr_kernel(
    const float* __restrict__ x,
    const unsigned short* __restrict__ es1w, const float* __restrict__ es1b,
    const unsigned short* __restrict__ es2w, const float* __restrict__ es2b,
    const unsigned short* __restrict__ rf1w, const float* __restrict__ rf1b,
    const unsigned short* __restrict__ rf2w, const float* __restrict__ rf2b,
    const unsigned short* __restrict__ rf3w, const float* __restrict__ rf3b,
    const float* __restrict__ ps1w,          const float* __restrict__ ps1b,
    const unsigned short* __restrict__ ps2w, const float* __restrict__ ps2b,
    const float* __restrict__ gw,            const float* __restrict__ gb,
    const unsigned short* __restrict__ xs1w, const float* __restrict__ xs1b,
    const unsigned short* __restrict__ xs2w, const float* __restrict__ xs2b,
    const float* __restrict__ xfw,           const float* __restrict__ xfb,
    float* __restrict__ out) {
  __shared__ __align__(16) unsigned short P[64 * AST];
  __shared__ __align__(16) unsigned short Q[64 * AST];
  __shared__ float probs[64 * 8];
  __shared__ float yacc[64];
  __shared__ float predw[8 * 64];

  const int t  = threadIdx.x;
  const int r0 = blockIdx.x * 64;

  // Stage 0: positional encoding in f32 -> P[b][0..64)
  // 512 threads: row=t&63, g=t>>6 (0..7): c=g&3 input dim, jh=g>>2 freq half
  {
    const int row = t & 63, g = t >> 6, c = g & 3, jh = g >> 2;
    const float xv = x[(r0 + row) * 4 + c];
    const float PIf = 3.14159265358979f;
#pragma unroll
    for (int jj = 0; jj < 4; jj++) {
      const int j = jh * 4 + jj;
      float ang = xv * (PIf * (float)(1 << j));
      P[row * AST + c * 16 + j]     = f2bf(__sinf(ang));
      P[row * AST + c * 16 + 8 + j] = f2bf(__cosf(ang));
    }
    if (t < 64) yacc[t] = 0.f;
  }
  __syncthreads();
  wgemm_s<64, 128, 0>(P, P, 64, es1w, es1b, nullptr);       // h1 -> P[64,192)
  __syncthreads();
  wgemm_s<128, 256, 0>(P + 64, Q, 0, es2w, es2b, nullptr);  // h  -> Q[0,256)
  __syncthreads();
  wgemm_s<256, 128, 1>(Q, P, 0, rf1w, rf1b, nullptr);       // r1 -> P[0,128)
  __syncthreads();
  wgemm_s<128, 128, 1>(P, P, 128, rf2w, rf2b, nullptr);     // r2 -> P[128,256)
  __syncthreads();
  wgemm_s<128, 256, 2>(P + 128, Q, 0, rf3w, rf3b, Q);       // enc_feat -> Q
  __syncthreads();
  // pol_s1 (K=4) in f32: pf1 -> P[0,128). 512 threads: 16 outputs each.
  {
    const int row = t & 63, g = t >> 6;
    const float xv0 = x[(r0 + row) * 4 + 0];
    const float xv1 = x[(r0 + row) * 4 + 1];
    const float xv2 = x[(r0 + row) * 4 + 2];
    const float xv3 = x[(r0 + row) * 4 + 3];
    for (int i = 0; i < 16; i++) {
      int o = g * 16 + i;
      float z = xv0 * ps1w[o * 4 + 0] + xv1 * ps1w[o * 4 + 1] +
                xv2 * ps1w[o * 4 + 2] + xv3 * ps1w[o * 4 + 3] + ps1b[o];
      P[row * AST + o] = f2bf(__sinf(OMEGA_F * z));
    }
  }
  __syncthreads();
  wgemm_s<128, 128, 0>(P, P, 128, ps2w, ps2b, nullptr);     // pf -> P[128,256)
  __syncthreads();
  // gate (f32 weights): 8 partial-threads per row (48 k each)
  {
    const int row = t >> 3, pp = t & 7;
    float lg[7];
#pragma unroll
    for (int j = 0; j < 7; j++) {
      float s = 0.f;
      for (int kk = pp * 48; kk < pp * 48 + 48; ++kk) {
        float v = (kk < 256) ? bf2f(Q[row * AST + kk])
                             : bf2f(P[row * AST + 128 + (kk - 256)]);
        s += v * gw[j * 384 + kk];
      }
      s += __shfl_xor(s, 1);
      s += __shfl_xor(s, 2);
      s += __shfl_xor(s, 4);
      lg[j] = s;
    }
    if (pp == 0) {
#pragma unroll
      for (int j = 0; j < 7; j++) probs[row * 8 + j] = lg[j] + gb[j];
    }
  }
  __syncthreads();
  if (t < 64) {  // softmax over 7
    float m = probs[t * 8];
#pragma unroll
    for (int j = 1; j < 7; j++) m = fmaxf(m, probs[t * 8 + j]);
    float s = 0.f, e[7];
#pragma unroll
    for (int j = 0; j < 7; j++) { e[j] = __expf(probs[t * 8 + j] - m); s += e[j]; }
    float inv = 1.f / s;
#pragma unroll
    for (int j = 0; j < 7; j++) probs[t * 8 + j] = e[j] * inv;
  }
  // experts: enc_feat stays in Q; e1 -> P[0,256); e2+final fused in registers
  for (int ex = 0; ex < 7; ++ex) {
    __syncthreads();
    wgemm_s<256, 256, 0>(Q, P, 0, xs1w + ex * 65536, xs1b + ex * 256, nullptr);
    __syncthreads();
    wexpert2_s(P, xs2w + ex * 65536, xs2b + ex * 256, xfw + ex * 256, predw);
    __syncthreads();
    if (t < 64) {
      float s = 0.f;
#pragma unroll
      for (int w = 0; w < 8; w++) s += predw[w * 64 + t];
      yacc[t] += (s + xfb[ex]) * probs[t * 8 + ex];
    }
  }
  __syncthreads();
  if (t < 64) out[r0 + t] = yacc[t];
}

extern "C" void kernel_launch(void* const* d_in, const int* in_sizes, int n_in,
                              void* d_out, int out_size, void* d_ws, size_t ws_size,
                              hipStream_t stream) {
  (void)out_size; (void)n_in; (void)ws_size;
  const int idx[N_CVT] = {1, 3, 5, 7, 9, 13, 17, 19};
  unsigned off[N_CVT], cur = 0;
  CvtArgs a;
  for (int i = 0; i < N_CVT; i++) {
    off[i] = cur;
    a.src[i] = (const float*)d_in[idx[i]];
    a.off[i] = cur;
    a.n[i]   = (unsigned)in_sizes[idx[i]];
    cur += ((unsigned)in_sizes[idx[i]] + 7u) & ~7u;  // 16B-align each array
  }
  unsigned short* dst = (unsigned short*)d_ws;
  hipLaunchKernelGGL(convert_kernel, dim3(512), dim3(256), 0, stream, a, dst);
  hipLaunchKernelGGL(moe_inr_kernel, dim3(65536 / 64), dim3(512), 0, stream,
      (const float*)d_in[0],
      dst + off[0], (const float*)d_in[2],
      dst + off[1], (const float*)d_in[4],
      dst + off[2], (const float*)d_in[6],
      dst + off[3], (const float*)d_in[8],
      dst + off[4], (const float*)d_in[10],
      (const float*)d_in[11], (const float*)d_in[12],
      dst + off[5], (const float*)d_in[14],
      (const float*)d_in[15], (const float*)d_in[16],
      dst + off[6], (const float*)d_in[18],
      dst + off[7], (const float*)d_in[20],
      (const float*)d_in[21], (const float*)d_in[22],
      (float*)d_out);
}